// Round 1
// baseline (341.600 us; speedup 1.0000x reference)
//
#include <hip/hip_runtime.h>

#define BB 8
#define CC 128
#define HH 64
#define WW 64
#define K2 9
#define NOFF 18   // 2 * K2

// ---------------------------------------------------------------------------
// Kernel 1: 3x3 offset conv (C=128 -> 18) + base grid + pixel-coord transform.
// One thread per (b,h,w) pixel; computes all 18 conv outputs; writes
// (gx, gy) pixel coords per tap to ws as float2 [B][K2][H][W].
// ---------------------------------------------------------------------------
__global__ __launch_bounds__(256) void offset_grid_kernel(
    const float* __restrict__ x,      // [B,C,H,W]
    const float* __restrict__ offw,   // [18,C,3,3]
    const float* __restrict__ offb,   // [18]
    float* __restrict__ grid)         // [B,K2,H,W] float2
{
    int idx = blockIdx.x * blockDim.x + threadIdx.x;
    if (idx >= BB * HH * WW) return;
    int w = idx % WW;
    int h = (idx / WW) % HH;
    int b = idx / (HH * WW);

    float acc[NOFF];
#pragma unroll
    for (int o = 0; o < NOFF; ++o) acc[o] = offb[o];

    for (int c = 0; c < CC; ++c) {
        const float* xp = x + ((size_t)(b * CC + c) * HH) * WW;
        float xv[9];
#pragma unroll
        for (int dh = -1; dh <= 1; ++dh) {
#pragma unroll
            for (int dw = -1; dw <= 1; ++dw) {
                int hh = h + dh, ww2 = w + dw;
                float v = 0.f;
                if (hh >= 0 && hh < HH && ww2 >= 0 && ww2 < WW)
                    v = xp[hh * WW + ww2];
                xv[(dh + 1) * 3 + (dw + 1)] = v;
            }
        }
#pragma unroll
        for (int o = 0; o < NOFF; ++o) {
            const float* wp = offw + (size_t)(o * CC + c) * 9;
#pragma unroll
            for (int j = 0; j < 9; ++j)
                acc[o] = fmaf(xv[j], wp[j], acc[o]);
        }
    }

    float base_x = -1.f + (2.0f / (WW - 1)) * (float)w;
    float base_y = -1.f + (2.0f / (HH - 1)) * (float)h;

#pragma unroll
    for (int t = 0; t < K2; ++t) {
        float gx = ((acc[t]      + base_x + 1.f) * (float)WW - 1.f) * 0.5f;
        float gy = ((acc[K2 + t] + base_y + 1.f) * (float)HH - 1.f) * 0.5f;
        size_t gi = ((((size_t)b * K2 + t) * HH + h) * WW + w) * 2;
        grid[gi]     = gx;
        grid[gi + 1] = gy;
    }
}

// ---------------------------------------------------------------------------
// Kernel 2: bilinear sample (zeros padding) + per-(channel,tap) weighted sum.
// One thread per output element (b,c,h,w); lanes span w -> coalesced.
// ---------------------------------------------------------------------------
__global__ __launch_bounds__(256) void sample_kernel(
    const float* __restrict__ x,     // [B,C,H,W]
    const float* __restrict__ grid,  // [B,K2,H,W] float2
    const float* __restrict__ wk,    // [C,K2]
    float* __restrict__ out)         // [B,C,H,W]
{
    int idx = blockIdx.x * blockDim.x + threadIdx.x;
    if (idx >= BB * CC * HH * WW) return;
    int w = idx % WW;
    int h = (idx / WW) % HH;
    int c = (idx / (HH * WW)) % CC;
    int b = idx / (CC * HH * WW);

    const float* xp = x + ((size_t)(b * CC + c) * HH) * WW;
    const float2* gp = (const float2*)grid;

    float acc = 0.f;
#pragma unroll
    for (int t = 0; t < K2; ++t) {
        size_t gi = (((size_t)b * K2 + t) * HH + h) * WW + w;
        float2 g = gp[gi];
        float gx = g.x, gy = g.y;

        float x0f = floorf(gx), y0f = floorf(gy);
        float wx1 = gx - x0f, wx0 = 1.f - wx1;
        float wy1 = gy - y0f, wy0 = 1.f - wy1;
        int ix0 = (int)x0f, iy0 = (int)y0f;
        int ix1 = ix0 + 1,  iy1 = iy0 + 1;

        bool x0ok = (ix0 >= 0) & (ix0 < WW);
        bool x1ok = (ix1 >= 0) & (ix1 < WW);
        bool y0ok = (iy0 >= 0) & (iy0 < HH);
        bool y1ok = (iy1 >= 0) & (iy1 < HH);

        float v00 = 0.f, v10 = 0.f, v01 = 0.f, v11 = 0.f;
        if (y0ok) {
            const float* row = xp + (size_t)iy0 * WW;
            if (x0ok) v00 = row[ix0];
            if (x1ok) v10 = row[ix1];
        }
        if (y1ok) {
            const float* row = xp + (size_t)iy1 * WW;
            if (x0ok) v01 = row[ix0];
            if (x1ok) v11 = row[ix1];
        }

        float bil = v00 * (wx0 * wy0) + v10 * (wx1 * wy0)
                  + v01 * (wx0 * wy1) + v11 * (wx1 * wy1);
        acc = fmaf(bil, wk[c * K2 + t], acc);
    }
    out[idx] = acc;
}

extern "C" void kernel_launch(void* const* d_in, const int* in_sizes, int n_in,
                              void* d_out, int out_size, void* d_ws, size_t ws_size,
                              hipStream_t stream) {
    const float* x    = (const float*)d_in[0];   // [8,128,64,64]
    const float* offw = (const float*)d_in[1];   // [18,128,3,3]
    const float* offb = (const float*)d_in[2];   // [18]
    const float* ww   = (const float*)d_in[3];   // [1,128,3,3] -> [C,K2]
    float* out  = (float*)d_out;                 // [8,128,64,64]
    float* grid = (float*)d_ws;                  // [8,9,64,64] float2 = 2.36 MB

    int n1 = BB * HH * WW;            // 32768
    int n2 = BB * CC * HH * WW;       // 4194304

    hipLaunchKernelGGL(offset_grid_kernel, dim3((n1 + 255) / 256), dim3(256),
                       0, stream, x, offw, offb, grid);
    hipLaunchKernelGGL(sample_kernel, dim3((n2 + 255) / 256), dim3(256),
                       0, stream, x, grid, ww, out);
}

// Round 2
// 138.280 us; speedup vs baseline: 2.4704x; 2.4704x over previous
//
#include <hip/hip_runtime.h>

#define BB 8
#define CC 128
#define HH 64
#define WW 64
#define K2 9
#define NOFF 18          // 2*K2
#define HW (HH*WW)       // 4096
#define NPIX (BB*HW)     // 32768
#define NCHUNK 8
#define CPC (CC/NCHUNK)  // 16 channels per chunk

// ---------------------------------------------------------------------------
// K0: transpose x [B,C,H,W] -> xT [B,H*W,C]  (coalesced both sides via LDS)
// ---------------------------------------------------------------------------
__global__ __launch_bounds__(256) void transpose_kernel(
    const float* __restrict__ x, float* __restrict__ xT)
{
    __shared__ float tile[32][33];
    int b  = blockIdx.z;
    int c0 = blockIdx.y * 32;
    int p0 = blockIdx.x * 32;
    int tx = threadIdx.x;   // 0..31
    int ty = threadIdx.y;   // 0..7
#pragma unroll
    for (int i = 0; i < 4; ++i) {
        int c = c0 + ty + i * 8;
        tile[ty + i * 8][tx] = x[((size_t)(b * CC + c)) * HW + p0 + tx];
    }
    __syncthreads();
#pragma unroll
    for (int i = 0; i < 4; ++i) {
        int p = p0 + ty + i * 8;
        xT[((size_t)b * HW + p) * CC + c0 + tx] = tile[tx][ty + i * 8];
    }
}

// ---------------------------------------------------------------------------
// K1: offset conv partials. Block = 256 pixels x 1 channel-chunk (16 ch).
// Weights for the chunk staged in LDS (wave-uniform reads -> broadcast).
// part layout: [chunk][o][pixel]
// ---------------------------------------------------------------------------
__global__ __launch_bounds__(256) void offset_partial_kernel(
    const float* __restrict__ x, const float* __restrict__ offw,
    float* __restrict__ part)
{
    __shared__ float sw[NOFF * CPC * 9];   // 2592 floats = 10.4 KB
    int chunk = blockIdx.y;
    int c0 = chunk * CPC;
    int tid = threadIdx.x;
    for (int i = tid; i < NOFF * CPC * 9; i += 256) {
        int o = i / (CPC * 9);
        int r = i % (CPC * 9);
        int cc = r / 9, j = r % 9;
        sw[i] = offw[((size_t)(o * CC + c0 + cc)) * 9 + j];
    }
    __syncthreads();

    int pixel = blockIdx.x * 256 + tid;
    int w = pixel & (WW - 1);
    int h = (pixel >> 6) & (HH - 1);
    int b = pixel >> 12;

    float acc[NOFF];
#pragma unroll
    for (int o = 0; o < NOFF; ++o) acc[o] = 0.f;

    for (int cc = 0; cc < CPC; ++cc) {
        const float* xp = x + ((size_t)(b * CC + c0 + cc)) * HW;
        float xv[9];
#pragma unroll
        for (int dh = -1; dh <= 1; ++dh) {
#pragma unroll
            for (int dw = -1; dw <= 1; ++dw) {
                int hh = h + dh, ww2 = w + dw;
                float v = 0.f;
                if (hh >= 0 && hh < HH && ww2 >= 0 && ww2 < WW)
                    v = xp[hh * WW + ww2];
                xv[(dh + 1) * 3 + (dw + 1)] = v;
            }
        }
        const float* swc = &sw[cc * 9];
#pragma unroll
        for (int o = 0; o < NOFF; ++o) {
#pragma unroll
            for (int j = 0; j < 9; ++j)
                acc[o] = fmaf(xv[j], swc[o * CPC * 9 + j], acc[o]);
        }
    }
#pragma unroll
    for (int o = 0; o < NOFF; ++o)
        part[((size_t)(chunk * NOFF + o)) * NPIX + pixel] = acc[o];
}

// ---------------------------------------------------------------------------
// K1b: reduce partials over chunks, add bias, transform to pixel coords.
// grid2: float2 per (b,tap,h,w)
// ---------------------------------------------------------------------------
__global__ __launch_bounds__(256) void reduce_grid_kernel(
    const float* __restrict__ part, const float* __restrict__ offb,
    float2* __restrict__ grid2)
{
    int pixel = blockIdx.x * 256 + threadIdx.x;
    int t = blockIdx.y;
    float sx = offb[t], sy = offb[t + K2];
#pragma unroll
    for (int ch = 0; ch < NCHUNK; ++ch) {
        sx += part[((size_t)(ch * NOFF + t)) * NPIX + pixel];
        sy += part[((size_t)(ch * NOFF + t + K2)) * NPIX + pixel];
    }
    int w = pixel & 63, h = (pixel >> 6) & 63, b = pixel >> 12;
    float base_x = -1.f + (2.f / (WW - 1)) * (float)w;
    float base_y = -1.f + (2.f / (HH - 1)) * (float)h;
    float gx = ((sx + base_x + 1.f) * (float)WW - 1.f) * 0.5f;
    float gy = ((sy + base_y + 1.f) * (float)HH - 1.f) * 0.5f;
    grid2[((size_t)(b * K2 + t)) * HW + (pixel & (HW - 1))] = make_float2(gx, gy);
}

// ---------------------------------------------------------------------------
// K2: bilinear sample from xT (lanes across channels -> coalesced gathers),
// tap-weighted sum; LDS transpose tile for coalesced [B,C,H,W] stores.
// Block = 16 w-pixels x 128 channels (8 passes of 2 pixels).
// ---------------------------------------------------------------------------
__global__ __launch_bounds__(256) void sample_kernel(
    const float* __restrict__ xT, const float2* __restrict__ grid2,
    const float* __restrict__ wk, float* __restrict__ out)
{
    __shared__ float acc_t[CC * 17];   // [c][16 px + pad]
    int tid = threadIdx.x;
    int c  = tid & 127;
    int p2 = tid >> 7;                 // 0/1: which pixel of the pair
    int pixel_base = blockIdx.x * 16;
    int b = pixel_base >> 12;
    int rem_base = pixel_base & 4095;  // h*64 + w0, w0 multiple of 16
    int h  = rem_base >> 6;
    int w0 = rem_base & 63;

    float wk_r[K2];
#pragma unroll
    for (int t = 0; t < K2; ++t) wk_r[t] = wk[c * K2 + t];

    const float* xb = xT + (size_t)b * HW * CC;

#pragma unroll 1
    for (int pp = 0; pp < 8; ++pp) {
        int slot = pp * 2 + p2;
        int rem = rem_base + slot;     // same h row (w0+15 <= 63)
        float acc = 0.f;
#pragma unroll
        for (int t = 0; t < K2; ++t) {
            float2 g = grid2[((size_t)(b * K2 + t)) * HW + rem];
            float gx = g.x, gy = g.y;
            float x0f = floorf(gx), y0f = floorf(gy);
            float wx1 = gx - x0f, wx0 = 1.f - wx1;
            float wy1 = gy - y0f, wy0 = 1.f - wy1;
            int ix0 = (int)x0f, iy0 = (int)y0f;
            int ix1 = ix0 + 1,  iy1 = iy0 + 1;
            bool x0ok = (unsigned)ix0 < WW;
            bool x1ok = (unsigned)ix1 < WW;
            bool y0ok = (unsigned)iy0 < HH;
            bool y1ok = (unsigned)iy1 < HH;
            float v00 = 0.f, v10 = 0.f, v01 = 0.f, v11 = 0.f;
            if (y0ok) {
                const float* row = xb + ((size_t)iy0 * WW) * CC;
                if (x0ok) v00 = row[ix0 * CC + c];
                if (x1ok) v10 = row[ix1 * CC + c];
            }
            if (y1ok) {
                const float* row = xb + ((size_t)iy1 * WW) * CC;
                if (x0ok) v01 = row[ix0 * CC + c];
                if (x1ok) v11 = row[ix1 * CC + c];
            }
            float bil = v00 * (wx0 * wy0) + v10 * (wx1 * wy0)
                      + v01 * (wx0 * wy1) + v11 * (wx1 * wy1);
            acc = fmaf(bil, wk_r[t], acc);
        }
        acc_t[c * 17 + slot] = acc;
    }
    __syncthreads();
#pragma unroll
    for (int r = 0; r < 8; ++r) {
        int cs   = r * 16 + (tid >> 4);
        int wloc = tid & 15;
        out[((size_t)(b * CC + cs)) * HW + h * WW + w0 + wloc] = acc_t[cs * 17 + wloc];
    }
}

// ---------------------------------------------------------------------------
// Fallback kernels (round-1 versions) if ws_size is too small for the staged
// pipeline (needs ~21.3 MB). Round-1 passed with 2.36 MB.
// ---------------------------------------------------------------------------
__global__ __launch_bounds__(256) void offset_grid_kernel_fb(
    const float* __restrict__ x, const float* __restrict__ offw,
    const float* __restrict__ offb, float* __restrict__ grid)
{
    int idx = blockIdx.x * blockDim.x + threadIdx.x;
    if (idx >= NPIX) return;
    int w = idx & 63, h = (idx >> 6) & 63, b = idx >> 12;
    float acc[NOFF];
#pragma unroll
    for (int o = 0; o < NOFF; ++o) acc[o] = offb[o];
    for (int c = 0; c < CC; ++c) {
        const float* xp = x + ((size_t)(b * CC + c)) * HW;
        float xv[9];
#pragma unroll
        for (int dh = -1; dh <= 1; ++dh)
#pragma unroll
            for (int dw = -1; dw <= 1; ++dw) {
                int hh = h + dh, ww2 = w + dw;
                float v = 0.f;
                if (hh >= 0 && hh < HH && ww2 >= 0 && ww2 < WW) v = xp[hh * WW + ww2];
                xv[(dh + 1) * 3 + (dw + 1)] = v;
            }
#pragma unroll
        for (int o = 0; o < NOFF; ++o) {
            const float* wp = offw + (size_t)(o * CC + c) * 9;
#pragma unroll
            for (int j = 0; j < 9; ++j) acc[o] = fmaf(xv[j], wp[j], acc[o]);
        }
    }
    float base_x = -1.f + (2.f / (WW - 1)) * (float)w;
    float base_y = -1.f + (2.f / (HH - 1)) * (float)h;
#pragma unroll
    for (int t = 0; t < K2; ++t) {
        float gx = ((acc[t]      + base_x + 1.f) * (float)WW - 1.f) * 0.5f;
        float gy = ((acc[K2 + t] + base_y + 1.f) * (float)HH - 1.f) * 0.5f;
        size_t gi = ((((size_t)b * K2 + t) * HH + h) * WW + w) * 2;
        grid[gi] = gx; grid[gi + 1] = gy;
    }
}

__global__ __launch_bounds__(256) void sample_kernel_fb(
    const float* __restrict__ x, const float* __restrict__ grid,
    const float* __restrict__ wk, float* __restrict__ out)
{
    int idx = blockIdx.x * blockDim.x + threadIdx.x;
    if (idx >= BB * CC * HW) return;
    int w = idx & 63, h = (idx >> 6) & 63;
    int c = (idx / HW) & 127, b = idx / (CC * HW);
    const float* xp = x + ((size_t)(b * CC + c)) * HW;
    const float2* gp = (const float2*)grid;
    float acc = 0.f;
#pragma unroll
    for (int t = 0; t < K2; ++t) {
        float2 g = gp[(((size_t)b * K2 + t)) * HW + h * WW + w];
        float gx = g.x, gy = g.y;
        float x0f = floorf(gx), y0f = floorf(gy);
        float wx1 = gx - x0f, wx0 = 1.f - wx1;
        float wy1 = gy - y0f, wy0 = 1.f - wy1;
        int ix0 = (int)x0f, iy0 = (int)y0f;
        int ix1 = ix0 + 1,  iy1 = iy0 + 1;
        float v00 = 0.f, v10 = 0.f, v01 = 0.f, v11 = 0.f;
        if ((unsigned)iy0 < HH) {
            const float* row = xp + (size_t)iy0 * WW;
            if ((unsigned)ix0 < WW) v00 = row[ix0];
            if ((unsigned)ix1 < WW) v10 = row[ix1];
        }
        if ((unsigned)iy1 < HH) {
            const float* row = xp + (size_t)iy1 * WW;
            if ((unsigned)ix0 < WW) v01 = row[ix0];
            if ((unsigned)ix1 < WW) v11 = row[ix1];
        }
        float bil = v00 * (wx0 * wy0) + v10 * (wx1 * wy0)
                  + v01 * (wx0 * wy1) + v11 * (wx1 * wy1);
        acc = fmaf(bil, wk[c * K2 + t], acc);
    }
    out[idx] = acc;
}

extern "C" void kernel_launch(void* const* d_in, const int* in_sizes, int n_in,
                              void* d_out, int out_size, void* d_ws, size_t ws_size,
                              hipStream_t stream) {
    const float* x    = (const float*)d_in[0];   // [8,128,64,64]
    const float* offw = (const float*)d_in[1];   // [18,128,3,3]
    const float* offb = (const float*)d_in[2];   // [18]
    const float* wwk  = (const float*)d_in[3];   // [1,128,3,3] -> [C,9]
    float* out = (float*)d_out;

    const size_t GRID_BYTES = (size_t)NPIX * K2 * 2 * sizeof(float);      // 2.36 MB
    const size_t PART_BYTES = (size_t)NCHUNK * NOFF * NPIX * sizeof(float); // 18.9 MB
    const size_t NEED = GRID_BYTES + PART_BYTES;                           // 21.2 MB

    if (ws_size < NEED) {
        // fallback: round-1 pipeline (needs only 2.36 MB)
        float* grid = (float*)d_ws;
        hipLaunchKernelGGL(offset_grid_kernel_fb, dim3(NPIX / 256), dim3(256),
                           0, stream, x, offw, offb, grid);
        hipLaunchKernelGGL(sample_kernel_fb, dim3((BB * CC * HW) / 256), dim3(256),
                           0, stream, x, grid, wwk, out);
        return;
    }

    float2* grid2 = (float2*)d_ws;
    float*  regA  = (float*)((char*)d_ws + GRID_BYTES);  // partials, then xT
    float*  part  = regA;
    float*  xT    = regA;   // reused after reduce_grid consumed partials

    // K1: conv partials (parallel over channel chunks)
    hipLaunchKernelGGL(offset_partial_kernel, dim3(NPIX / 256, NCHUNK), dim3(256),
                       0, stream, x, offw, part);
    // K1b: reduce + coord transform
    hipLaunchKernelGGL(reduce_grid_kernel, dim3(NPIX / 256, K2), dim3(256),
                       0, stream, part, offb, grid2);
    // K0: transpose x -> xT (overwrites partials region; stream-ordered)
    hipLaunchKernelGGL(transpose_kernel, dim3(HW / 32, CC / 32, BB), dim3(32, 8),
                       0, stream, x, xT);
    // K2: coalesced bilinear sample + weighted tap sum
    hipLaunchKernelGGL(sample_kernel, dim3(NPIX / 16), dim3(256),
                       0, stream, xT, grid2, wwk, out);
}

// Round 3
// 89.284 us; speedup vs baseline: 3.8260x; 1.5488x over previous
//
#include <hip/hip_runtime.h>

#define BB 8
#define CC 128
#define HH 64
#define WW 64
#define K2 9
#define NOFF 18
#define HW (HH*WW)       // 4096
#define NPIX (BB*HW)     // 32768

// ---------------------------------------------------------------------------
// K1: offset conv (C=128 -> 18) + coord transform, one kernel.
// Block = one pixel row (64 px) x 4 channel-quarters (32 ch each).
// Weight addresses are wave-uniform (readfirstlane on quarter id) -> s_load,
// FMA = v_fmac with SGPR operand. LDS reduce over quarters, then transform.
// blockIdx.x: b = j&7 (XCD-local batch), h = j>>3.
// ---------------------------------------------------------------------------
__global__ __launch_bounds__(256) void offset_kernel(
    const float* __restrict__ x, const float* __restrict__ offw,
    const float* __restrict__ offb, float2* __restrict__ grid2)
{
    __shared__ float sred[NOFF * 4 * 64];   // [o][q][pix] = 18 KB
    int j = blockIdx.x;        // 0..511
    int b = j & 7;
    int h = j >> 3;            // 0..63
    int tid = threadIdx.x;
    int pixw = tid & 63;       // w coordinate (lane)
    int q = __builtin_amdgcn_readfirstlane(tid >> 6);   // 0..3, wave-uniform

    const float* xb = x + ((size_t)(b * CC + q * 32)) * HW;
    float acc[NOFF];
#pragma unroll
    for (int o = 0; o < NOFF; ++o) acc[o] = 0.f;

    for (int cc = 0; cc < 32; ++cc) {
        const float* xp = xb + (size_t)cc * HW;
        float xv[9];
#pragma unroll
        for (int dh = -1; dh <= 1; ++dh) {
            int hh = h + dh;
            bool hok = (unsigned)hh < HH;
#pragma unroll
            for (int dw = -1; dw <= 1; ++dw) {
                int ww2 = pixw + dw;
                bool ok = hok && ((unsigned)ww2 < WW);
                xv[(dh + 1) * 3 + (dw + 1)] = ok ? xp[hh * WW + ww2] : 0.f;
            }
        }
        const float* wp = offw + (size_t)(q * 32 + cc) * 9;  // uniform address
#pragma unroll
        for (int o = 0; o < NOFF; ++o) {
            const float* wpo = wp + (size_t)o * CC * 9;
#pragma unroll
            for (int jj = 0; jj < 9; ++jj)
                acc[o] = fmaf(xv[jj], wpo[jj], acc[o]);
        }
    }
#pragma unroll
    for (int o = 0; o < NOFF; ++o)
        sred[(o * 4 + q) * 64 + pixw] = acc[o];
    __syncthreads();

    // 576 items = 64 pix x 9 taps
    for (int item = tid; item < 576; item += 256) {
        int p = item & 63;
        int t = item >> 6;
        float sx = offb[t], sy = offb[t + K2];
#pragma unroll
        for (int qq = 0; qq < 4; ++qq) {
            sx += sred[(t * 4 + qq) * 64 + p];
            sy += sred[((t + K2) * 4 + qq) * 64 + p];
        }
        float base_x = -1.f + (2.f / (WW - 1)) * (float)p;
        float base_y = -1.f + (2.f / (HH - 1)) * (float)h;
        float gx = ((sx + base_x + 1.f) * (float)WW - 1.f) * 0.5f;
        float gy = ((sy + base_y + 1.f) * (float)HH - 1.f) * 0.5f;
        grid2[((size_t)(b * K2 + t)) * HW + h * WW + p] = make_float2(gx, gy);
    }
}

// ---------------------------------------------------------------------------
// K0: transpose x [B,C,H,W] -> xT [B,H*W,C]
// ---------------------------------------------------------------------------
__global__ __launch_bounds__(256) void transpose_kernel(
    const float* __restrict__ x, float* __restrict__ xT)
{
    __shared__ float tile[32][33];
    int b  = blockIdx.z;
    int c0 = blockIdx.y * 32;
    int p0 = blockIdx.x * 32;
    int tx = threadIdx.x;
    int ty = threadIdx.y;
#pragma unroll
    for (int i = 0; i < 4; ++i)
        tile[ty + i * 8][tx] = x[((size_t)(b * CC + c0 + ty + i * 8)) * HW + p0 + tx];
    __syncthreads();
#pragma unroll
    for (int i = 0; i < 4; ++i)
        xT[((size_t)b * HW + p0 + ty + i * 8) * CC + c0 + tx] = tile[tx][ty + i * 8];
}

// ---------------------------------------------------------------------------
// K2: bilinear sample + tap-weighted sum.
// Phase A: 144 threads compute per-(pixel,tap) records (masked corner-weight
//          float4 + packed clamped indices int2) into LDS once per block.
// Phase B: lanes span channels; per tap = 2 broadcast LDS reads + 4 coalesced
//          gathers from xT + 5 FMA. XCD swizzle: b = blockIdx.x & 7.
// ---------------------------------------------------------------------------
__global__ __launch_bounds__(256) void sample_kernel(
    const float* __restrict__ xT, const float2* __restrict__ grid2,
    const float* __restrict__ wk, float* __restrict__ out)
{
    __shared__ float4 recW[144];
    __shared__ int2   recI[144];
    __shared__ float  acc_t[CC * 17];

    int j = blockIdx.x;            // 0..2047
    int b = j & 7;
    int rem_base = (j >> 3) * 16;  // h*64 + w0 within batch
    int h  = rem_base >> 6;
    int w0 = rem_base & 63;

    int tid = threadIdx.x;
    int c  = tid & 127;
    int p2 = tid >> 7;

    if (tid < 144) {
        int slot = tid & 15;
        int tap  = tid >> 4;
        float2 g = grid2[((size_t)(b * K2 + tap)) * HW + rem_base + slot];
        float gx = g.x, gy = g.y;
        float x0f = floorf(gx), y0f = floorf(gy);
        float wx1 = gx - x0f, wx0 = 1.f - wx1;
        float wy1 = gy - y0f, wy0 = 1.f - wy1;
        int ix0 = (int)x0f, iy0 = (int)y0f;
        int ix1 = ix0 + 1,  iy1 = iy0 + 1;
        float ax0 = ((unsigned)ix0 < WW) ? wx0 : 0.f;
        float ax1 = ((unsigned)ix1 < WW) ? wx1 : 0.f;
        float ay0 = ((unsigned)iy0 < HH) ? wy0 : 0.f;
        float ay1 = ((unsigned)iy1 < HH) ? wy1 : 0.f;
        int cx0 = min(max(ix0, 0), WW - 1), cx1 = min(max(ix1, 0), WW - 1);
        int cy0 = min(max(iy0, 0), HH - 1), cy1 = min(max(iy1, 0), HH - 1);
        int o00 = cy0 * WW + cx0, o10 = cy0 * WW + cx1;
        int o01 = cy1 * WW + cx0, o11 = cy1 * WW + cx1;
        recW[tid] = make_float4(ax0 * ay0, ax1 * ay0, ax0 * ay1, ax1 * ay1);
        recI[tid] = make_int2(o00 | (o10 << 16), o01 | (o11 << 16));
    }
    __syncthreads();

    float wk_r[K2];
#pragma unroll
    for (int t = 0; t < K2; ++t) wk_r[t] = wk[c * K2 + t];

    const float* xb = xT + (size_t)b * HW * CC;

#pragma unroll 1
    for (int pp = 0; pp < 8; ++pp) {
        int slot = pp * 2 + p2;          // wave-uniform
        float acc = 0.f;
#pragma unroll
        for (int t = 0; t < K2; ++t) {
            int r = t * 16 + slot;
            float4 wv = recW[r];
            int2   iv = recI[r];
            float v00 = xb[((iv.x & 0xFFFF) << 7) + c];
            float v10 = xb[((iv.x >> 16)    << 7) + c];
            float v01 = xb[((iv.y & 0xFFFF) << 7) + c];
            float v11 = xb[((iv.y >> 16)    << 7) + c];
            float bil = v00 * wv.x + v10 * wv.y + v01 * wv.z + v11 * wv.w;
            acc = fmaf(bil, wk_r[t], acc);
        }
        acc_t[c * 17 + slot] = acc;
    }
    __syncthreads();
#pragma unroll
    for (int r = 0; r < 8; ++r) {
        int cs   = r * 16 + (tid >> 4);
        int wloc = tid & 15;
        out[((size_t)(b * CC + cs)) * HW + h * WW + w0 + wloc] = acc_t[cs * 17 + wloc];
    }
}

// ---------------------------------------------------------------------------
// Fallback (round-1 pipeline, needs only 2.36 MB ws) — defensive only.
// ---------------------------------------------------------------------------
__global__ __launch_bounds__(256) void offset_grid_kernel_fb(
    const float* __restrict__ x, const float* __restrict__ offw,
    const float* __restrict__ offb, float* __restrict__ grid)
{
    int idx = blockIdx.x * blockDim.x + threadIdx.x;
    if (idx >= NPIX) return;
    int w = idx & 63, h = (idx >> 6) & 63, b = idx >> 12;
    float acc[NOFF];
#pragma unroll
    for (int o = 0; o < NOFF; ++o) acc[o] = offb[o];
    for (int c = 0; c < CC; ++c) {
        const float* xp = x + ((size_t)(b * CC + c)) * HW;
        float xv[9];
#pragma unroll
        for (int dh = -1; dh <= 1; ++dh)
#pragma unroll
            for (int dw = -1; dw <= 1; ++dw) {
                int hh = h + dh, ww2 = w + dw;
                float v = 0.f;
                if (hh >= 0 && hh < HH && ww2 >= 0 && ww2 < WW) v = xp[hh * WW + ww2];
                xv[(dh + 1) * 3 + (dw + 1)] = v;
            }
#pragma unroll
        for (int o = 0; o < NOFF; ++o) {
            const float* wp = offw + (size_t)(o * CC + c) * 9;
#pragma unroll
            for (int jj = 0; jj < 9; ++jj) acc[o] = fmaf(xv[jj], wp[jj], acc[o]);
        }
    }
    float base_x = -1.f + (2.f / (WW - 1)) * (float)w;
    float base_y = -1.f + (2.f / (HH - 1)) * (float)h;
#pragma unroll
    for (int t = 0; t < K2; ++t) {
        float gx = ((acc[t]      + base_x + 1.f) * (float)WW - 1.f) * 0.5f;
        float gy = ((acc[K2 + t] + base_y + 1.f) * (float)HH - 1.f) * 0.5f;
        size_t gi = ((((size_t)b * K2 + t) * HH + h) * WW + w) * 2;
        grid[gi] = gx; grid[gi + 1] = gy;
    }
}

__global__ __launch_bounds__(256) void sample_kernel_fb(
    const float* __restrict__ x, const float* __restrict__ grid,
    const float* __restrict__ wk, float* __restrict__ out)
{
    int idx = blockIdx.x * blockDim.x + threadIdx.x;
    if (idx >= BB * CC * HW) return;
    int w = idx & 63, h = (idx >> 6) & 63;
    int c = (idx / HW) & 127, b = idx / (CC * HW);
    const float* xp = x + ((size_t)(b * CC + c)) * HW;
    const float2* gp = (const float2*)grid;
    float acc = 0.f;
#pragma unroll
    for (int t = 0; t < K2; ++t) {
        float2 g = gp[(((size_t)b * K2 + t)) * HW + h * WW + w];
        float gx = g.x, gy = g.y;
        float x0f = floorf(gx), y0f = floorf(gy);
        float wx1 = gx - x0f, wx0 = 1.f - wx1;
        float wy1 = gy - y0f, wy0 = 1.f - wy1;
        int ix0 = (int)x0f, iy0 = (int)y0f;
        int ix1 = ix0 + 1,  iy1 = iy0 + 1;
        float v00 = 0.f, v10 = 0.f, v01 = 0.f, v11 = 0.f;
        if ((unsigned)iy0 < HH) {
            const float* row = xp + (size_t)iy0 * WW;
            if ((unsigned)ix0 < WW) v00 = row[ix0];
            if ((unsigned)ix1 < WW) v10 = row[ix1];
        }
        if ((unsigned)iy1 < HH) {
            const float* row = xp + (size_t)iy1 * WW;
            if ((unsigned)ix0 < WW) v01 = row[ix0];
            if ((unsigned)ix1 < WW) v11 = row[ix1];
        }
        float bil = v00 * (wx0 * wy0) + v10 * (wx1 * wy0)
                  + v01 * (wx0 * wy1) + v11 * (wx1 * wy1);
        acc = fmaf(bil, wk[c * K2 + t], acc);
    }
    out[idx] = acc;
}

extern "C" void kernel_launch(void* const* d_in, const int* in_sizes, int n_in,
                              void* d_out, int out_size, void* d_ws, size_t ws_size,
                              hipStream_t stream) {
    const float* x    = (const float*)d_in[0];
    const float* offw = (const float*)d_in[1];
    const float* offb = (const float*)d_in[2];
    const float* wwk  = (const float*)d_in[3];
    float* out = (float*)d_out;

    const size_t GRID_BYTES = (size_t)NPIX * K2 * 2 * sizeof(float);  // 2.36 MB
    const size_t XT_BYTES   = (size_t)NPIX * CC * sizeof(float);      // 16.8 MB
    const size_t NEED = GRID_BYTES + XT_BYTES;                        // 19.2 MB

    if (ws_size < NEED) {
        float* grid = (float*)d_ws;
        hipLaunchKernelGGL(offset_grid_kernel_fb, dim3(NPIX / 256), dim3(256),
                           0, stream, x, offw, offb, grid);
        hipLaunchKernelGGL(sample_kernel_fb, dim3((BB * CC * HW) / 256), dim3(256),
                           0, stream, x, grid, wwk, out);
        return;
    }

    float2* grid2 = (float2*)d_ws;
    float*  xT    = (float*)((char*)d_ws + GRID_BYTES);

    hipLaunchKernelGGL(offset_kernel, dim3(NPIX / 64), dim3(256),
                       0, stream, x, offw, offb, grid2);
    hipLaunchKernelGGL(transpose_kernel, dim3(HW / 32, CC / 32, BB), dim3(32, 8),
                       0, stream, x, xT);
    hipLaunchKernelGGL(sample_kernel, dim3(NPIX / 16), dim3(256),
                       0, stream, xT, grid2, wwk, out);
}